// Round 3
// baseline (155.397 us; speedup 1.0000x reference)
//
#include <hip/hip_runtime.h>

constexpr int T   = 16384;  // tokens
constexpr int HD  = 4096;   // hidden dim
constexpr int E   = 64;     // experts
constexpr int BK  = 32;     // k per chunk
constexpr int NCH = HD / BK;  // 128 chunks

using short8 = __attribute__((ext_vector_type(8))) short;
using f32x4  = __attribute__((ext_vector_type(4))) float;

__device__ __forceinline__ unsigned short f2bf(float x) {
  union { float f; unsigned u; } v; v.f = x;
  return (unsigned short)((v.u + 0x7FFFu + ((v.u >> 16) & 1u)) >> 16);
}
__device__ __forceinline__ float bf2f(unsigned short h) {
  union { float f; unsigned u; } v; v.u = ((unsigned)h) << 16;
  return v.f;
}

// ---------------------------------------------------------------------------
// Kernel 0: pack W (fp32 [64][4096]) into bf16 hi/lo image, plain layout:
// img[chunk 128][expert 64][slot 8] x 16B; slot 0..3 = hi k-groups, 4..7 = lo.
// ---------------------------------------------------------------------------
__global__ __launch_bounds__(256) void wprep(const float* __restrict__ W,
                                             short* __restrict__ img) {
  const int tid = blockIdx.x * 256 + threadIdx.x;   // 0..65535
  const int c   = tid >> 9;
  const int rem = tid & 511;
  const int e   = rem >> 3;
  const int sp  = rem & 7;
  const int part = sp >> 2;   // 0 = hi, 1 = lo
  const int sl   = sp & 3;    // k-group
  const float* src = W + (size_t)e * HD + c * BK + sl * 8;
  short8 v;
#pragma unroll
  for (int j = 0; j < 8; ++j) {
    float x = src[j];
    unsigned short h = f2bf(x);
    v[j] = part ? (short)f2bf(x - bf2f(h)) : (short)h;
  }
  *(short8*)(img + (size_t)tid * 8) = v;
}

// ---------------------------------------------------------------------------
// Kernel 1: logits = H x W^T (split-bf16 MFMA, 3 terms), LDS-free.
// 256 blocks x 4 waves; wave gw owns rows 16*gw..16*gw+15, all 64 experts.
// A: global->reg depth-4 prefetch (HBM). B: global->reg depth-2 (L2 image).
// Fused epilogue: per-row softmax top-2 + renorm (16-lane butterfly).
// ---------------------------------------------------------------------------
__global__ __launch_bounds__(256, 1) void router_gemm(
    const float* __restrict__ H, const short* __restrict__ img,
    float* __restrict__ logits, float* __restrict__ topw, float* __restrict__ topi) {
  const int w    = threadIdx.x >> 6;
  const int lane = threadIdx.x & 63;
  const int q    = lane >> 4;   // k-group / C row-group
  const int r    = lane & 15;   // A row / B col (expert) sub-index
  const int gw   = blockIdx.x * 4 + w;           // 0..1023

  const float* pA = H + (size_t)(gw * 16 + r) * HD + q * 8;
  const short* pB = img + r * 64 + q * 8;        // + ct*1024 + t*4096 (+32 for lo)

  f32x4  Ab[4][2];        // depth-4 A prefetch (raw fp32)
  short8 Bh[2][4], Bl[2][4];  // depth-2 B prefetch
  f32x4  acc[4];
#pragma unroll
  for (int ct = 0; ct < 4; ++ct)
#pragma unroll
    for (int i = 0; i < 4; ++i) acc[ct][i] = 0.f;

  auto cvt = [&](f32x4 a0, f32x4 a1, short8& hi, short8& lo) {
#pragma unroll
    for (int j = 0; j < 4; ++j) {
      unsigned short h0 = f2bf(a0[j]);
      hi[j] = (short)h0; lo[j] = (short)f2bf(a0[j] - bf2f(h0));
      unsigned short h1 = f2bf(a1[j]);
      hi[4 + j] = (short)h1; lo[4 + j] = (short)f2bf(a1[j] - bf2f(h1));
    }
  };

  // prologue: A(0..3), B(0..1)
#pragma unroll
  for (int i = 0; i < 4; ++i) {
    Ab[i][0] = *(const f32x4*)(pA + i * BK);
    Ab[i][1] = *(const f32x4*)(pA + i * BK + 4);
  }
#pragma unroll
  for (int i = 0; i < 2; ++i)
#pragma unroll
    for (int ct = 0; ct < 4; ++ct) {
      Bh[i][ct] = *(const short8*)(pB + ct * 1024 + (size_t)i * 4096);
      Bl[i][ct] = *(const short8*)(pB + ct * 1024 + (size_t)i * 4096 + 32);
    }

#define GEMM_BODY(U, TT, PREA, PREB)                                            \
  {                                                                             \
    f32x4 a0 = Ab[U][0], a1 = Ab[U][1];                                         \
    short8 bh0 = Bh[(U)&1][0], bh1 = Bh[(U)&1][1],                              \
           bh2 = Bh[(U)&1][2], bh3 = Bh[(U)&1][3];                              \
    short8 bl0 = Bl[(U)&1][0], bl1 = Bl[(U)&1][1],                              \
           bl2 = Bl[(U)&1][2], bl3 = Bl[(U)&1][3];                              \
    if (PREA) {                                                                 \
      Ab[U][0] = *(const f32x4*)(pA + ((TT) + 4) * BK);                         \
      Ab[U][1] = *(const f32x4*)(pA + ((TT) + 4) * BK + 4);                     \
    }                                                                           \
    if (PREB) {                                                                 \
      _Pragma("unroll")                                                         \
      for (int ct = 0; ct < 4; ++ct) {                                          \
        Bh[(U)&1][ct] = *(const short8*)(pB + ct * 1024 + (size_t)((TT) + 2) * 4096);      \
        Bl[(U)&1][ct] = *(const short8*)(pB + ct * 1024 + (size_t)((TT) + 2) * 4096 + 32); \
      }                                                                         \
    }                                                                           \
    short8 ahi, alo;                                                            \
    cvt(a0, a1, ahi, alo);                                                      \
    acc[0] = __builtin_amdgcn_mfma_f32_16x16x32_bf16(ahi, bh0, acc[0], 0, 0, 0);\
    acc[0] = __builtin_amdgcn_mfma_f32_16x16x32_bf16(alo, bh0, acc[0], 0, 0, 0);\
    acc[0] = __builtin_amdgcn_mfma_f32_16x16x32_bf16(ahi, bl0, acc[0], 0, 0, 0);\
    acc[1] = __builtin_amdgcn_mfma_f32_16x16x32_bf16(ahi, bh1, acc[1], 0, 0, 0);\
    acc[1] = __builtin_amdgcn_mfma_f32_16x16x32_bf16(alo, bh1, acc[1], 0, 0, 0);\
    acc[1] = __builtin_amdgcn_mfma_f32_16x16x32_bf16(ahi, bl1, acc[1], 0, 0, 0);\
    acc[2] = __builtin_amdgcn_mfma_f32_16x16x32_bf16(ahi, bh2, acc[2], 0, 0, 0);\
    acc[2] = __builtin_amdgcn_mfma_f32_16x16x32_bf16(alo, bh2, acc[2], 0, 0, 0);\
    acc[2] = __builtin_amdgcn_mfma_f32_16x16x32_bf16(ahi, bl2, acc[2], 0, 0, 0);\
    acc[3] = __builtin_amdgcn_mfma_f32_16x16x32_bf16(ahi, bh3, acc[3], 0, 0, 0);\
    acc[3] = __builtin_amdgcn_mfma_f32_16x16x32_bf16(alo, bh3, acc[3], 0, 0, 0);\
    acc[3] = __builtin_amdgcn_mfma_f32_16x16x32_bf16(ahi, bl3, acc[3], 0, 0, 0);\
  }

  for (int t0 = 0; t0 <= NCH - 8; t0 += 4) {   // t0 = 0..120
    GEMM_BODY(0, t0 + 0, true, true)
    GEMM_BODY(1, t0 + 1, true, true)
    GEMM_BODY(2, t0 + 2, true, true)
    GEMM_BODY(3, t0 + 3, true, true)
  }
  // tail: t = 124..127 (A all resident; B(126),B(127) still to prefetch)
  GEMM_BODY(0, 124, false, true)
  GEMM_BODY(1, 125, false, true)
  GEMM_BODY(2, 126, false, false)
  GEMM_BODY(3, 127, false, false)
#undef GEMM_BODY

  // --- epilogue: logits write + fused softmax/top-2 ---
  const int orow = gw * 16 + 4 * q;
#pragma unroll
  for (int ct = 0; ct < 4; ++ct)
#pragma unroll
    for (int rr = 0; rr < 4; ++rr)
      logits[(size_t)(orow + rr) * E + 16 * ct + r] = acc[ct][rr];

#pragma unroll
  for (int rr = 0; rr < 4; ++rr) {
    // top-1 over raw logits (softmax is monotone); min-index tiebreak
    float v1 = acc[0][rr]; int i1 = r;
    { float x = acc[1][rr]; if (x > v1) { v1 = x; i1 = 16 + r; } }
    { float x = acc[2][rr]; if (x > v1) { v1 = x; i1 = 32 + r; } }
    { float x = acc[3][rr]; if (x > v1) { v1 = x; i1 = 48 + r; } }
#pragma unroll
    for (int off = 1; off < 16; off <<= 1) {
      float ov = __shfl_xor(v1, off); int oi = __shfl_xor(i1, off);
      if (ov > v1 || (ov == v1 && oi < i1)) { v1 = ov; i1 = oi; }
    }
    // top-2: exclude i1
    float v2 = -3.4e38f; int i2 = 0;
#pragma unroll
    for (int ct = 0; ct < 4; ++ct) {
      int idx = 16 * ct + r; float x = acc[ct][rr];
      if (idx != i1 && x > v2) { v2 = x; i2 = idx; }
    }
#pragma unroll
    for (int off = 1; off < 16; off <<= 1) {
      float ov = __shfl_xor(v2, off); int oi = __shfl_xor(i2, off);
      if (ov > v2 || (ov == v2 && oi < i2)) { v2 = ov; i2 = oi; }
    }
    if (r == 0) {
      // renormalized pair: w1 = p1/(p1+p2) = 1/(1+e^{x2-x1}); softmax denom cancels
      float d  = __expf(v2 - v1);
      float w1 = 1.0f / (1.0f + d);
      const int R = orow + rr;
      topw[(size_t)R * 2 + 0] = w1;
      topw[(size_t)R * 2 + 1] = 1.0f - w1;
      topi[(size_t)R * 2 + 0] = (float)i1;
      topi[(size_t)R * 2 + 1] = (float)i2;
    }
  }
}

extern "C" void kernel_launch(void* const* d_in, const int* in_sizes, int n_in,
                              void* d_out, int out_size, void* d_ws, size_t ws_size,
                              hipStream_t stream) {
  const float* H = (const float*)d_in[0];  // [16384, 4096] fp32
  const float* W = (const float*)d_in[1];  // [64, 4096] fp32

  float* out    = (float*)d_out;
  float* topw   = out;                       // [16384, 2]
  float* logits = out + (size_t)T * 2;       // [16384, 64]
  float* topi   = logits + (size_t)T * E;    // [16384, 2] (indices as float)

  short* wimg = (short*)d_ws;                // 1 MiB image in workspace

  wprep<<<256, 256, 0, stream>>>(W, wimg);
  router_gemm<<<256, 256, 0, stream>>>(H, wimg, logits, topw, topi);
}

// Round 4
// 87.802 us; speedup vs baseline: 1.7698x; 1.7698x over previous
//
#include <hip/hip_runtime.h>

constexpr int T   = 16384;  // tokens
constexpr int HD  = 4096;   // hidden dim
constexpr int E   = 64;     // experts
constexpr int BK  = 64;     // k per chunk
constexpr int NCH = HD / BK;  // 64 chunks
constexpr int BM  = 32;     // rows per block

using short8 = __attribute__((ext_vector_type(8))) short;
using f32x4  = __attribute__((ext_vector_type(4))) float;

#define AS1 __attribute__((address_space(1)))
#define AS3 __attribute__((address_space(3)))

__device__ __forceinline__ unsigned short f2bf(float x) {
  union { float f; unsigned u; } v; v.f = x;
  return (unsigned short)((v.u + 0x7FFFu + ((v.u >> 16) & 1u)) >> 16);
}
__device__ __forceinline__ float bf2f(unsigned short h) {
  union { float f; unsigned u; } v; v.u = ((unsigned)h) << 16;
  return v.f;
}

__device__ __forceinline__ void gload16(const void* g, void* l) {
  __builtin_amdgcn_global_load_lds((const AS1 void*)g, (AS3 void*)l, 16, 0, 0);
}

// ---------------------------------------------------------------------------
// Kernel 0: pack W (fp32 [64][4096]) into bf16 hi/lo image per BK=64 chunk:
// img[chunk 64][expert 64][slot' 16] x 16B. Logical slot s: 0..7 = hi k-group
// s (8 bf16 of k [8s..8s+8)), 8..15 = lo of group s-8. Stored slot'
// sp = (s&8) | ((s&7) ^ (e&7))  (bank swizzle baked into the image).
// ---------------------------------------------------------------------------
__global__ __launch_bounds__(256) void wprep(const float* __restrict__ W,
                                             short* __restrict__ img) {
  const int tid = blockIdx.x * 256 + threadIdx.x;   // 0..65535 slots
  const int c    = tid >> 10;          // chunk 0..63
  const int e    = (tid >> 4) & 63;    // expert
  const int sp   = tid & 15;           // stored slot
  const int part = sp >> 3;            // 0 = hi, 1 = lo
  const int g    = (sp & 7) ^ (e & 7); // logical k-group
  const float* src = W + (size_t)e * HD + c * BK + g * 8;
  short8 v;
#pragma unroll
  for (int j = 0; j < 8; ++j) {
    float x = src[j];
    unsigned short h = f2bf(x);
    v[j] = part ? (short)f2bf(x - bf2f(h)) : (short)h;
  }
  *(short8*)(img + (size_t)tid * 8) = v;
}

// ---------------------------------------------------------------------------
// Kernel 1: logits = H x W^T (split-bf16 MFMA, 3 terms) + fused top-2.
// 512 blocks x 512 threads (8 waves), BM=32 rows, 2 blocks/CU -> 16 waves/CU.
// Wave w: row-tile rt=w>>2 (16 rows), col-tile ct=w&3 (16 experts); one 16x16
// output tile, 6 MFMA per BK=64 chunk. DMA staging: A fp32 triple-buffered
// (depth-2), B image double-buffered (depth-1); steady-state vmcnt(1).
// A LDS rows XOR-swizzled (pre-swizzled DMA source + swizzled ds_read).
// ---------------------------------------------------------------------------
__global__ __launch_bounds__(512, 4) void router_gemm(
    const float* __restrict__ H, const short* __restrict__ img,
    float* __restrict__ logits, float* __restrict__ topw, float* __restrict__ topi) {
  // A: 3 x 8 KB @ 0; B: 2 x 16 KB @ 24 KB; cand: 2 KB @ 56 KB
  __shared__ __align__(16) char lds[59392];
  char* const ldsA = lds;
  char* const ldsB = lds + 24576;
  float* const cand = (float*)(lds + 57344);  // [32 rows][4 ct][v1,i1,v2,i2]

  const int tid  = threadIdx.x;
  const int w    = tid >> 6;
  const int lane = tid & 63;
  const int q    = lane >> 4;   // 0..3
  const int r    = lane & 15;   // 0..15
  const int rt   = w >> 2;      // row-tile 0..1
  const int ct   = w & 3;       // col-tile 0..3
  const int row0 = blockIdx.x * BM;

  f32x4 acc = {0.f, 0.f, 0.f, 0.f};

  // --- staging: per wave 1 A-DMA + 2 B-DMA per chunk (wave-uniform LDS base) ---
  auto stageA = [&](int c, int buf) {
    // slot i = tid covers (row R = i>>4, stored slot sp = i&15); logical
    // s = (sp&8) | ((sp&7)^(R&7)); source pre-swizzled, LDS linear.
    const int R  = tid >> 4;
    const int sp = tid & 15;
    const int s  = (sp & 8) | ((sp & 7) ^ (R & 7));
    const char* src = (const char*)(H + (size_t)(row0 + R) * HD + c * BK) + s * 16;
    gload16(src, ldsA + buf * 8192 + w * 1024);  // HW adds lane*16
  };
  auto stageB = [&](int c, int buf) {
    const char* srcb = (const char*)img + (size_t)c * 16384;
    char* dstb = ldsB + buf * 16384;
#pragma unroll
    for (int j = 0; j < 2; ++j)
      gload16(srcb + (size_t)(j * 512 + tid) * 16, dstb + (j * 512 + w * 64) * 16);
  };

  const int Arow = 16 * rt + r;
  const int ra   = r & 7;    // (16rt+r)&7 == (16ct+r)&7 == r&7

  auto compute = [&](int abuf, int bbuf) {
    const char* Ab = ldsA + abuf * 8192 + Arow * 256;
    const char* Bb = ldsB + bbuf * 16384 + (16 * ct + r) * 256;
#pragma unroll
    for (int kk = 0; kk < 2; ++kk) {
      const int s0  = 8 * kk + 2 * q;
      const int sp0 = (s0 & 8) | ((s0 & 7) ^ ra);
      const int s1  = s0 + 1;
      const int sp1 = (s1 & 8) | ((s1 & 7) ^ ra);
      f32x4 a0 = *(const f32x4*)(Ab + sp0 * 16);
      f32x4 a1 = *(const f32x4*)(Ab + sp1 * 16);
      const int gh  = 4 * kk + q;
      const int sph = gh ^ ra;
      short8 bh = *(const short8*)(Bb + sph * 16);
      short8 bl = *(const short8*)(Bb + (8 | sph) * 16);
      short8 ahi, alo;
#pragma unroll
      for (int j = 0; j < 4; ++j) {
        unsigned short h0 = f2bf(a0[j]);
        ahi[j] = (short)h0; alo[j] = (short)f2bf(a0[j] - bf2f(h0));
        unsigned short h1 = f2bf(a1[j]);
        ahi[4 + j] = (short)h1; alo[4 + j] = (short)f2bf(a1[j] - bf2f(h1));
      }
      acc = __builtin_amdgcn_mfma_f32_16x16x32_bf16(ahi, bh, acc, 0, 0, 0);
      acc = __builtin_amdgcn_mfma_f32_16x16x32_bf16(alo, bh, acc, 0, 0, 0);
      acc = __builtin_amdgcn_mfma_f32_16x16x32_bf16(ahi, bl, acc, 0, 0, 0);
    }
  };

  // --- prologue: A(0), B(0), A(1) -> 4 outstanding per wave ---
  stageA(0, 0);
  stageB(0, 0);
  stageA(1, 1);

  int ab = 0, bb = 0;
  for (int t = 0; t < NCH - 2; ++t) {
    asm volatile("s_waitcnt vmcnt(1)\n\ts_barrier" ::: "memory");  // A(t),B(t) landed everywhere
    stageB(t + 1, bb ^ 1);
    int ab2 = ab + 2; if (ab2 >= 3) ab2 -= 3;
    stageA(t + 2, ab2);
    compute(ab, bb);
    ab = (ab == 2) ? 0 : ab + 1;
    bb ^= 1;
  }
  // t = NCH-2
  asm volatile("s_waitcnt vmcnt(1)\n\ts_barrier" ::: "memory");
  stageB(NCH - 1, bb ^ 1);
  compute(ab, bb);
  ab = (ab == 2) ? 0 : ab + 1;
  bb ^= 1;
  // t = NCH-1
  asm volatile("s_waitcnt vmcnt(0)\n\ts_barrier" ::: "memory");
  compute(ab, bb);

  // --- epilogue: logits write (D layout: col = lane&15, row = 4q+rr) ---
  const int orow0 = row0 + 16 * rt + 4 * q;
#pragma unroll
  for (int rr = 0; rr < 4; ++rr)
    logits[(size_t)(orow0 + rr) * E + 16 * ct + r] = acc[rr];

  // per-wave top-2 over this wave's 16 experts, for each of its 4 rows
#pragma unroll
  for (int rr = 0; rr < 4; ++rr) {
    const int myi = 16 * ct + r;
    float v1 = acc[rr]; int i1 = myi;
#pragma unroll
    for (int off = 1; off < 16; off <<= 1) {
      float ov = __shfl_xor(v1, off); int oi = __shfl_xor(i1, off);
      if (ov > v1 || (ov == v1 && oi < i1)) { v1 = ov; i1 = oi; }
    }
    float v2 = (myi == i1) ? -3.4e38f : acc[rr]; int i2 = myi;
#pragma unroll
    for (int off = 1; off < 16; off <<= 1) {
      float ov = __shfl_xor(v2, off); int oi = __shfl_xor(i2, off);
      if (ov > v2 || (ov == v2 && oi < i2)) { v2 = ov; i2 = oi; }
    }
    if (r == 0) {
      float* cd = cand + ((size_t)(16 * rt + 4 * q + rr) * 4 + ct) * 4;
      cd[0] = v1; cd[1] = (float)i1; cd[2] = v2; cd[3] = (float)i2;
    }
  }
  __syncthreads();

  // merge 4 col-tile candidate pairs per row; renormalized top-2 weights
  if (tid < BM) {
    const float* cd = cand + (size_t)tid * 16;   // 8 (v,i) pairs
    float bv = -3.4e38f; int bi = 1 << 30;
#pragma unroll
    for (int j = 0; j < 8; ++j) {
      float v = cd[2 * j]; int i = (int)cd[2 * j + 1];
      if (v > bv || (v == bv && i < bi)) { bv = v; bi = i; }
    }
    float sv = -3.4e38f; int si = 1 << 30;
#pragma unroll
    for (int j = 0; j < 8; ++j) {
      float v = cd[2 * j]; int i = (int)cd[2 * j + 1];
      if (i != bi && (v > sv || (v == sv && i < si))) { sv = v; si = i; }
    }
    // w1 = p1/(p1+p2) = 1/(1+e^{x2-x1}); softmax denominator cancels
    const float w1 = 1.0f / (1.0f + __expf(sv - bv));
    const int R = row0 + tid;
    topw[(size_t)R * 2 + 0] = w1;
    topw[(size_t)R * 2 + 1] = 1.0f - w1;
    topi[(size_t)R * 2 + 0] = (float)bi;
    topi[(size_t)R * 2 + 1] = (float)si;
  }
}

extern "C" void kernel_launch(void* const* d_in, const int* in_sizes, int n_in,
                              void* d_out, int out_size, void* d_ws, size_t ws_size,
                              hipStream_t stream) {
  const float* H = (const float*)d_in[0];  // [16384, 4096] fp32
  const float* W = (const float*)d_in[1];  // [64, 4096] fp32

  float* out    = (float*)d_out;
  float* topw   = out;                       // [16384, 2]
  float* logits = out + (size_t)T * 2;       // [16384, 64]
  float* topi   = logits + (size_t)T * E;    // [16384, 2] (indices as float)

  short* wimg = (short*)d_ws;                // 1 MiB packed W image

  wprep<<<256, 256, 0, stream>>>(W, wimg);
  router_gemm<<<T / BM, 512, 0, stream>>>(H, wimg, logits, topw, topi);
}

// Round 5
// 87.713 us; speedup vs baseline: 1.7716x; 1.0010x over previous
//
#include <hip/hip_runtime.h>
#include <hip/hip_bf16.h>

constexpr int T   = 16384;  // tokens
constexpr int HD  = 4096;   // hidden dim
constexpr int E   = 64;     // experts
constexpr int BK  = 64;     // k per chunk
constexpr int NCH = HD / BK;  // 64 chunks
constexpr int BM  = 32;     // rows per block

using short8 = __attribute__((ext_vector_type(8))) short;
using f32x4  = __attribute__((ext_vector_type(4))) float;

#define AS1 __attribute__((address_space(1)))
#define AS3 __attribute__((address_space(3)))

__device__ __forceinline__ unsigned short f2bf(float x) {
  union { float f; unsigned u; } v; v.f = x;
  return (unsigned short)((v.u + 0x7FFFu + ((v.u >> 16) & 1u)) >> 16);
}
__device__ __forceinline__ float bf2f(unsigned short h) {
  union { float f; unsigned u; } v; v.u = ((unsigned)h) << 16;
  return v.f;
}

__device__ __forceinline__ void gload16(const void* g, void* l) {
  __builtin_amdgcn_global_load_lds((const AS1 void*)g, (AS3 void*)l, 16, 0, 0);
}

// ---------------------------------------------------------------------------
// Kernel 0: pack W (fp32 [64][4096]) into bf16 hi/lo image per BK=64 chunk:
// img[chunk 64][expert 64][slot' 16] x 16B. Logical slot s: 0..7 = hi k-group
// s (8 bf16 of k [8s..8s+8)), 8..15 = lo of group s-8. Stored slot'
// sp = (s&8) | ((s&7) ^ (e&7))  (bank swizzle baked into the image).
// ---------------------------------------------------------------------------
__global__ __launch_bounds__(256) void wprep(const float* __restrict__ W,
                                             short* __restrict__ img) {
  const int tid = blockIdx.x * 256 + threadIdx.x;   // 0..65535 slots
  const int c    = tid >> 10;          // chunk 0..63
  const int e    = (tid >> 4) & 63;    // expert
  const int sp   = tid & 15;           // stored slot
  const int part = sp >> 3;            // 0 = hi, 1 = lo
  const int g    = (sp & 7) ^ (e & 7); // logical k-group
  const float* src = W + (size_t)e * HD + c * BK + g * 8;
  short8 v;
#pragma unroll
  for (int j = 0; j < 8; ++j) {
    float x = src[j];
    unsigned short h = f2bf(x);
    v[j] = part ? (short)f2bf(x - bf2f(h)) : (short)h;
  }
  *(short8*)(img + (size_t)tid * 8) = v;
}

// ---------------------------------------------------------------------------
// Kernel 1: logits = H x W^T (split-bf16 MFMA, 3 terms) + fused top-2.
// 512 blocks x 512 threads (8 waves), BM=32 rows, 2 blocks/CU -> 16 waves/CU.
// Wave w: row-tile rt=w>>2 (16 rows), col-tile ct=w&3 (16 experts).
// A and B both triple-buffered, staged at depth-2 (stage t+2 in iter t);
// steady-state vmcnt(3), never drained in the main loop. A-split uses HW
// v_cvt_pk_bf16_f32 via __float22bfloat162_rn (4x less VALU than bit-twiddle).
// ---------------------------------------------------------------------------
__global__ __launch_bounds__(512, 4) void router_gemm(
    const float* __restrict__ H, const short* __restrict__ img,
    float* __restrict__ logits, float* __restrict__ topw, float* __restrict__ topi) {
  // A: 3 x 8 KB @ 0; B: 3 x 16 KB @ 24 KB; cand: 2 KB @ 72 KB  (74 KB total)
  __shared__ __align__(16) char lds[75776];
  char* const ldsA = lds;
  char* const ldsB = lds + 24576;
  float* const cand = (float*)(lds + 73728);  // [32 rows][4 ct][v1,i1,v2,i2]

  const int tid  = threadIdx.x;
  const int w    = tid >> 6;
  const int lane = tid & 63;
  const int q    = lane >> 4;   // 0..3
  const int r    = lane & 15;   // 0..15
  const int rt   = w >> 2;      // row-tile 0..1
  const int ct   = w & 3;       // col-tile 0..3
  const int row0 = blockIdx.x * BM;

  f32x4 acc = {0.f, 0.f, 0.f, 0.f};

  // --- staging: per wave 1 A-DMA + 2 B-DMA per chunk (wave-uniform LDS base) ---
  auto stageA = [&](int c, int buf) {
    const int R  = tid >> 4;
    const int sp = tid & 15;
    const int s  = (sp & 8) | ((sp & 7) ^ (R & 7));
    const char* src = (const char*)(H + (size_t)(row0 + R) * HD + c * BK) + s * 16;
    gload16(src, ldsA + buf * 8192 + w * 1024);  // HW adds lane*16
  };
  auto stageB = [&](int c, int buf) {
    const char* srcb = (const char*)img + (size_t)c * 16384;
    char* dstb = ldsB + buf * 16384;
#pragma unroll
    for (int j = 0; j < 2; ++j)
      gload16(srcb + (size_t)(j * 512 + tid) * 16, dstb + (j * 512 + w * 64) * 16);
  };

  const int Arow = 16 * rt + r;
  const int ra   = r & 7;    // (16rt+r)&7 == (16ct+r)&7 == r&7

  // HW packed f32->bf16 split: hi = rne(x), lo = rne(x - hi)
  auto cvtpk = [&](float x, float y, unsigned& hw, unsigned& lw) {
    union { __hip_bfloat162 b; unsigned u; } Hh, Ll;
    Hh.b = __float22bfloat162_rn(float2{x, y});
    float2 hf = __bfloat1622float2(Hh.b);
    Ll.b = __float22bfloat162_rn(float2{x - hf.x, y - hf.y});
    hw = Hh.u; lw = Ll.u;
  };

  auto compute = [&](int abuf, int bbuf) {
    const char* Ab = ldsA + abuf * 8192 + Arow * 256;
    const char* Bb = ldsB + bbuf * 16384 + (16 * ct + r) * 256;
#pragma unroll
    for (int kk = 0; kk < 2; ++kk) {
      const int s0  = 8 * kk + 2 * q;
      const int sp0 = (s0 & 8) | ((s0 & 7) ^ ra);
      const int s1  = s0 + 1;
      const int sp1 = (s1 & 8) | ((s1 & 7) ^ ra);
      f32x4 a0 = *(const f32x4*)(Ab + sp0 * 16);
      f32x4 a1 = *(const f32x4*)(Ab + sp1 * 16);
      const int gh  = 4 * kk + q;
      const int sph = gh ^ ra;
      short8 bh = *(const short8*)(Bb + sph * 16);
      short8 bl = *(const short8*)(Bb + (8 | sph) * 16);
      union { short8 s; unsigned u[4]; } AH, AL;
      cvtpk(a0[0], a0[1], AH.u[0], AL.u[0]);
      cvtpk(a0[2], a0[3], AH.u[1], AL.u[1]);
      cvtpk(a1[0], a1[1], AH.u[2], AL.u[2]);
      cvtpk(a1[2], a1[3], AH.u[3], AL.u[3]);
      acc = __builtin_amdgcn_mfma_f32_16x16x32_bf16(AH.s, bh, acc, 0, 0, 0);
      acc = __builtin_amdgcn_mfma_f32_16x16x32_bf16(AL.s, bh, acc, 0, 0, 0);
      acc = __builtin_amdgcn_mfma_f32_16x16x32_bf16(AH.s, bl, acc, 0, 0, 0);
    }
  };

  // --- prologue: stage chunks 0 and 1 (6 DMAs outstanding per wave) ---
  stageA(0, 0);
  stageB(0, 0);
  stageA(1, 1);
  stageB(1, 1);

  int ab = 0, bb = 0;   // buffer index of chunk t (mod 3)
  for (int t = 0; t < NCH - 2; ++t) {
    // A(t),B(t) guaranteed landed; A(t+1),B(t+1) (3 DMAs) still in flight
    asm volatile("s_waitcnt vmcnt(3)\n\ts_barrier" ::: "memory");
    int nb = ab + 2; if (nb >= 3) nb -= 3;
    stageA(t + 2, nb);
    stageB(t + 2, nb);
    compute(ab, bb);
    ab = (ab == 2) ? 0 : ab + 1;
    bb = ab;
  }
  // t = NCH-2: A/B(NCH-1) still in flight
  asm volatile("s_waitcnt vmcnt(3)\n\ts_barrier" ::: "memory");
  compute(ab, bb);
  ab = (ab == 2) ? 0 : ab + 1;
  bb = ab;
  // t = NCH-1
  asm volatile("s_waitcnt vmcnt(0)\n\ts_barrier" ::: "memory");
  compute(ab, bb);

  // --- epilogue: logits write (D layout: col = lane&15, row = 4q+rr) ---
  const int orow0 = row0 + 16 * rt + 4 * q;
#pragma unroll
  for (int rr = 0; rr < 4; ++rr)
    logits[(size_t)(orow0 + rr) * E + 16 * ct + r] = acc[rr];

  // per-wave top-2 over this wave's 16 experts, for each of its 4 rows
#pragma unroll
  for (int rr = 0; rr < 4; ++rr) {
    const int myi = 16 * ct + r;
    float v1 = acc[rr]; int i1 = myi;
#pragma unroll
    for (int off = 1; off < 16; off <<= 1) {
      float ov = __shfl_xor(v1, off); int oi = __shfl_xor(i1, off);
      if (ov > v1 || (ov == v1 && oi < i1)) { v1 = ov; i1 = oi; }
    }
    float v2 = (myi == i1) ? -3.4e38f : acc[rr]; int i2 = myi;
#pragma unroll
    for (int off = 1; off < 16; off <<= 1) {
      float ov = __shfl_xor(v2, off); int oi = __shfl_xor(i2, off);
      if (ov > v2 || (ov == v2 && oi < i2)) { v2 = ov; i2 = oi; }
    }
    if (r == 0) {
      float* cd = cand + ((size_t)(16 * rt + 4 * q + rr) * 4 + ct) * 4;
      cd[0] = v1; cd[1] = (float)i1; cd[2] = v2; cd[3] = (float)i2;
    }
  }
  __syncthreads();

  // merge 4 col-tile candidate pairs per row; renormalized top-2 weights
  if (tid < BM) {
    const float* cd = cand + (size_t)tid * 16;   // 8 (v,i) pairs
    float bv = -3.4e38f; int bi = 1 << 30;
#pragma unroll
    for (int j = 0; j < 8; ++j) {
      float v = cd[2 * j]; int i = (int)cd[2 * j + 1];
      if (v > bv || (v == bv && i < bi)) { bv = v; bi = i; }
    }
    float sv = -3.4e38f; int si = 1 << 30;
#pragma unroll
    for (int j = 0; j < 8; ++j) {
      float v = cd[2 * j]; int i = (int)cd[2 * j + 1];
      if (i != bi && (v > sv || (v == sv && i < si))) { sv = v; si = i; }
    }
    // w1 = p1/(p1+p2) = 1/(1+e^{x2-x1}); softmax denominator cancels
    const float w1 = 1.0f / (1.0f + __expf(sv - bv));
    const int R = row0 + tid;
    topw[(size_t)R * 2 + 0] = w1;
    topw[(size_t)R * 2 + 1] = 1.0f - w1;
    topi[(size_t)R * 2 + 0] = (float)bi;
    topi[(size_t)R * 2 + 1] = (float)si;
  }
}

extern "C" void kernel_launch(void* const* d_in, const int* in_sizes, int n_in,
                              void* d_out, int out_size, void* d_ws, size_t ws_size,
                              hipStream_t stream) {
  const float* H = (const float*)d_in[0];  // [16384, 4096] fp32
  const float* W = (const float*)d_in[1];  // [64, 4096] fp32

  float* out    = (float*)d_out;
  float* topw   = out;                       // [16384, 2]
  float* logits = out + (size_t)T * 2;       // [16384, 64]
  float* topi   = logits + (size_t)T * E;    // [16384, 2] (indices as float)

  short* wimg = (short*)d_ws;                // 1 MiB packed W image

  wprep<<<256, 256, 0, stream>>>(W, wimg);
  router_gemm<<<T / BM, 512, 0, stream>>>(H, wimg, logits, topw, topi);
}